// Round 17
// baseline (420.286 us; speedup 1.0000x reference)
//
#include <hip/hip_runtime.h>
#include <math.h>

// ---------------------------------------------------------------------------
// EViT attention + top-k pruning. B=64, N=197, C=768, H=12, hd=64, keep=137.
//
// out (output 0): bf16 MFMA pipeline: cvt -> vzero -> qkv MFMA GEMM -> MFMA
//   flash -> proj MFMA GEMM.
// idx/index (outputs 1/2): FROZEN fp64 cls path + 8-ulp-bucket low-first
//   ranking. Per-value arithmetic bit-frozen since R7.
// R17 (mgemm): REGISTER-DIRECT, NO LDS. Four structural attempts (R9 dbuf,
//   R14 conflicts+addr, R15 occupancy, R16 depth-3) all null at ~100us,
//   MfmaUtil 18%, ~1250cy/step: the invariant is the per-step 4-wave
//   barrier convoy (cooperative LDS staging). Now each wave loads its own
//   fragments global->VGPR (ping-pong, unrolled, static indices), no
//   barriers, no LDS: waves fully decoupled, ~3 independent load streams
//   per SIMD. A/B panels L2-resident under the existing XCD swizzle.
// ---------------------------------------------------------------------------

typedef __attribute__((ext_vector_type(8))) short short8;
typedef __attribute__((ext_vector_type(4))) float f32x4;

constexpr int T_B = 64, T_N = 197, T_C = 768, T_H = 12, T_HD = 64;
constexpr int T_M = T_B * T_N;      // 12608
constexpr int T_KEEP = 137, T_NTOK = 196;

constexpr size_t OOFF_INDEX = (size_t)T_M * T_C;                        // 9,682,944
constexpr size_t OOFF_IDX   = OOFF_INDEX + (size_t)T_B * T_KEEP * T_C;  // 16,416,768

constexpr size_t U_XB_AO = 0;
constexpr size_t U_QWB   = 9682944;
constexpr size_t U_PWB   = 11452416;
constexpr size_t U_QB    = 12042240;
constexpr size_t U_KB    = 21725184;
constexpr size_t U_VB    = 31408128;          // vtg: 768*64*224 = 11,010,048 ushorts
constexpr size_t WS_FP_BYTE = 82182144ull;    // fp64 region (cls phase only)

__device__ __forceinline__ float bf2f(short u) {
  return __builtin_bit_cast(float, ((unsigned)(unsigned short)u) << 16);
}
__device__ __forceinline__ unsigned short f2bf(float f) {
  unsigned u = __builtin_bit_cast(unsigned, f);
  return (unsigned short)((u + 0x7fffu + ((u >> 16) & 1u)) >> 16);
}

// --------------------------- fp32 -> bf16 convert ---------------------------
__global__ __launch_bounds__(256) void cvt_k(const float* __restrict__ in,
                                             unsigned short* __restrict__ outp)
{
  const int i = blockIdx.x * 256 + threadIdx.x;
  const float4 v = ((const float4*)in)[i];
  const unsigned long long pk =
      (unsigned long long)f2bf(v.x) | ((unsigned long long)f2bf(v.y) << 16) |
      ((unsigned long long)f2bf(v.z) << 32) | ((unsigned long long)f2bf(v.w) << 48);
  ((unsigned long long*)outp)[i] = pk;
}

// --------------------------- vtg zero-fill ----------------------------------
__global__ __launch_bounds__(256) void vzero_k(unsigned short* __restrict__ vtg)
{
  const size_t i = ((size_t)blockIdx.x * 256 + threadIdx.x) * 8;
  *(short8*)(vtg + i) = (short8){0, 0, 0, 0, 0, 0, 0, 0};
}

// --------------------------- bf16 MFMA GEMM (R17: register-direct) -----------
// C[M,N] = A[M,768] @ B[N,768]^T. 128x128 tile, 4 waves each 64x64.
// No LDS: per-wave fragment loads global->VGPR, ping-pong prefetch, unrolled.
template<int MODE, int NTN>
__global__ __launch_bounds__(256) void mgemm_k(
    const unsigned short* __restrict__ A, const unsigned short* __restrict__ Bw,
    int M, float* __restrict__ outF, const float* __restrict__ bias,
    unsigned short* __restrict__ oq, unsigned short* __restrict__ ok,
    unsigned short* __restrict__ ov)
{
  const int t = threadIdx.x, w = t >> 6, lane = t & 63;
  const int wr = w >> 1, wc = w & 1;

  const int nwg = 99 * NTN;
  int id = blockIdx.x;
  {
    const int q = nwg >> 3, r = nwg & 7;
    const int xcd = id & 7, off = id >> 3;
    id = (xcd < r ? xcd * (q + 1) : r * (q + 1) + (xcd - r) * q) + off;
  }
  const int m0 = (id / NTN) * 128, n0 = (id % NTN) * 128;

  const int gsel = lane >> 4, rsel = lane & 15;
  const unsigned short* Ap[4];
  const unsigned short* Bp[4];
#pragma unroll
  for (int i = 0; i < 4; i++) {
    int ar = m0 + wr * 64 + i * 16 + rsel; ar = ar < M ? ar : M - 1;
    Ap[i] = A + (size_t)ar * 768 + gsel * 8;
    Bp[i] = Bw + (size_t)(n0 + wc * 64 + i * 16 + rsel) * 768 + gsel * 8;
  }

  f32x4 acc[4][4];
#pragma unroll
  for (int i = 0; i < 4; i++)
#pragma unroll
    for (int j = 0; j < 4; j++) acc[i][j] = (f32x4){0.f, 0.f, 0.f, 0.f};

  short8 aE[4], bE[4], aO[4], bO[4];
#pragma unroll
  for (int i = 0; i < 4; i++) {
    aE[i] = *(const short8*)(Ap[i]);
    bE[i] = *(const short8*)(Bp[i]);
  }

#pragma unroll
  for (int k = 0; k < 24; ++k) {
    if ((k & 1) == 0) {
      if (k + 1 < 24) {
#pragma unroll
        for (int i = 0; i < 4; i++) {
          aO[i] = *(const short8*)(Ap[i] + (k + 1) * 32);
          bO[i] = *(const short8*)(Bp[i] + (k + 1) * 32);
        }
      }
#pragma unroll
      for (int mi = 0; mi < 4; mi++)
#pragma unroll
        for (int ni = 0; ni < 4; ni++)
          acc[mi][ni] = __builtin_amdgcn_mfma_f32_16x16x32_bf16(aE[mi], bE[ni], acc[mi][ni], 0, 0, 0);
    } else {
      if (k + 1 < 24) {
#pragma unroll
        for (int i = 0; i < 4; i++) {
          aE[i] = *(const short8*)(Ap[i] + (k + 1) * 32);
          bE[i] = *(const short8*)(Bp[i] + (k + 1) * 32);
        }
      }
#pragma unroll
      for (int mi = 0; mi < 4; mi++)
#pragma unroll
        for (int ni = 0; ni < 4; ni++)
          acc[mi][ni] = __builtin_amdgcn_mfma_f32_16x16x32_bf16(aO[mi], bO[ni], acc[mi][ni], 0, 0, 0);
    }
  }

  const int colL = lane & 15, rowH = lane >> 4;
#pragma unroll
  for (int mi = 0; mi < 4; mi++) {
#pragma unroll
    for (int r = 0; r < 4; r++) {
      const int gm = m0 + wr * 64 + mi * 16 + rowH * 4 + r;
      if (gm >= M) continue;
      int bb = 0, nn = 0;
      if (MODE == 0) { bb = gm / T_N; nn = gm - bb * T_N; }
#pragma unroll
      for (int ni = 0; ni < 4; ni++) {
        const int gc = n0 + wc * 64 + ni * 16 + colL;
        const float val = acc[mi][ni][r];
        if (MODE == 0) {
          const int part = gc / T_C;
          const int rem = gc - part * T_C;
          const int h = rem >> 6, d = rem & 63;
          if (part == 2) {
            ov[(((size_t)(bb * T_H + h)) * 64 + d) * 224 + nn] = f2bf(val);
          } else {
            unsigned short* dst = part == 0 ? oq : ok;
            dst[(((size_t)(bb * T_H + h)) * T_N + nn) * T_HD + d] = f2bf(val);
          }
        } else {
          outF[(size_t)gm * T_C + gc] = val + bias[gc];
        }
      }
    }
  }
}

// --------------------------- MFMA flash attention (R12) ----------------------
__global__ __launch_bounds__(256) void flash3_k(
    const unsigned short* __restrict__ qb, const unsigned short* __restrict__ kb,
    const unsigned short* __restrict__ vtg, unsigned short* __restrict__ ao)
{
  __shared__ unsigned short lds[27456];   // K 12608 + 4 x P 3712
  constexpr int KL_U = 0;
  constexpr int PL0  = 12608;

  const int bh = blockIdx.x;
  const int b = bh / T_H, h = bh - b * T_H;
  const int t = threadIdx.x;
  const int w = t >> 6, lane = t & 63;
  const int colL = lane & 15, g4 = lane >> 4;
  const int PL_W = PL0 + w * 3712;
  const short8 z8 = (short8){0, 0, 0, 0, 0, 0, 0, 0};

  {
    const unsigned short* src = kb + (size_t)bh * T_N * 64;
    for (int c = t; c < 1576; c += 256) {
      const int row = c >> 3, s = c & 7;
      const short8 v = *(const short8*)(src + row * 64 + s * 8);
      *(short8*)&lds[KL_U + row * 64 + ((s ^ (row & 7)) * 8)] = v;
    }
  }
  if (lane < 16) {
    unsigned short* p = &lds[PL_W + lane * 232];
    *(short8*)&p[208] = z8; *(short8*)&p[216] = z8;
  }
  __syncthreads();

  const size_t qbase = (size_t)bh * T_N * 64;
  const unsigned short* vb2 = vtg + (size_t)bh * 64 * 224;

  for (int qt = w; qt < 13; qt += 4) {
    int qrow = qt * 16 + colL; if (qrow > 196) qrow = 196;
    const short8 qa0 = *(const short8*)(qb + qbase + (size_t)qrow * 64 + g4 * 8);
    const short8 qa1 = *(const short8*)(qb + qbase + (size_t)qrow * 64 + 32 + g4 * 8);

    f32x4 acc[13];
#pragma unroll
    for (int kt = 0; kt < 13; kt++) acc[kt] = (f32x4){0.f, 0.f, 0.f, 0.f};
#pragma unroll
    for (int kt = 0; kt < 13; kt++) {
      const int krow = kt * 16 + colL;
      const int base = KL_U + krow * 64;
      const short8 k0f = *(const short8*)&lds[base + ((g4 ^ (krow & 7)) * 8)];
      const short8 k1f = *(const short8*)&lds[base + (((4 + g4) ^ (krow & 7)) * 8)];
      acc[kt] = __builtin_amdgcn_mfma_f32_16x16x32_bf16(qa0, k0f, acc[kt], 0, 0, 0);
      acc[kt] = __builtin_amdgcn_mfma_f32_16x16x32_bf16(qa1, k1f, acc[kt], 0, 0, 0);
    }

    float l4[4];
#pragma unroll
    for (int r = 0; r < 4; r++) {
      float sv[13];
      float mx = -1e30f;
#pragma unroll
      for (int kt = 0; kt < 13; kt++) {
        const int col = kt * 16 + colL;
        float s = acc[kt][r] * 0.125f;
        if (col > 196) s = -1e30f;
        sv[kt] = s;
        mx = fmaxf(mx, s);
      }
      mx = fmaxf(mx, __shfl_xor(mx, 1));
      mx = fmaxf(mx, __shfl_xor(mx, 2));
      mx = fmaxf(mx, __shfl_xor(mx, 4));
      mx = fmaxf(mx, __shfl_xor(mx, 8));
      float l = 0.f;
      const int prow = g4 * 4 + r;
#pragma unroll
      for (int kt = 0; kt < 13; kt++) {
        const float p = __expf(sv[kt] - mx);
        l += p;
        lds[PL_W + prow * 232 + kt * 16 + colL] = f2bf(p);
      }
      l += __shfl_xor(l, 1);
      l += __shfl_xor(l, 2);
      l += __shfl_xor(l, 4);
      l += __shfl_xor(l, 8);
      l4[r] = l;
    }

    f32x4 oacc[4];
#pragma unroll
    for (int dt = 0; dt < 4; dt++) oacc[dt] = (f32x4){0.f, 0.f, 0.f, 0.f};
#pragma unroll
    for (int ks = 0; ks < 7; ks++) {
      const short8 pa = *(const short8*)&lds[PL_W + colL * 232 + ks * 32 + g4 * 8];
#pragma unroll
      for (int dt = 0; dt < 4; dt++) {
        const short8 vf = *(const short8*)(vb2 + (size_t)(dt * 16 + colL) * 224 + ks * 32 + g4 * 8);
        oacc[dt] = __builtin_amdgcn_mfma_f32_16x16x32_bf16(pa, vf, oacc[dt], 0, 0, 0);
      }
    }

#pragma unroll
    for (int r = 0; r < 4; r++) {
      const int row = qt * 16 + g4 * 4 + r;
      if (row <= 196) {
        const float invl = 1.f / l4[r];
        unsigned short* op = ao + ((size_t)b * T_N + row) * T_C + h * 64;
#pragma unroll
        for (int dt = 0; dt < 4; dt++)
          op[dt * 16 + colL] = f2bf(oacc[dt][r] * invl);
      }
    }
  }
}

// --------------------------- fp64 cls path (FROZEN arithmetic) ---------------
__global__ __launch_bounds__(256) void qcls_k(const float* __restrict__ x,
                                              const float* __restrict__ qkvw,
                                              double* __restrict__ qc)
{
  __shared__ double xr[768];
  const int b = blockIdx.x, t = threadIdx.x;
  if (t < 192) {
    const float4 v = *(const float4*)&x[(size_t)b * T_N * T_C + t * 4];
    xr[t * 4 + 0] = (double)v.x; xr[t * 4 + 1] = (double)v.y;
    xr[t * 4 + 2] = (double)v.z; xr[t * 4 + 3] = (double)v.w;
  }
  __syncthreads();
  const int w = t >> 6, lane = t & 63;
  const int jj0 = blockIdx.y * 4;
  for (int jj = jj0; jj < jj0 + 4; jj++) {
    const int j = jj * 4 + w;
    const float* wr = qkvw + (size_t)j * T_C;
    double a = 0.0;
#pragma unroll
    for (int ci = 0; ci < 12; ci++) a += xr[lane + ci * 64] * (double)wr[lane + ci * 64];
#pragma unroll
    for (int off = 32; off > 0; off >>= 1) a += __shfl_xor(a, off);
    if (lane == 0) qc[(size_t)b * T_C + j] = a;
  }
}

__global__ __launch_bounds__(256) void wtil_k(const double* __restrict__ qc,
                                              const float* __restrict__ qkvw,
                                              double* __restrict__ wt)
{
  __shared__ double ql[64];
  const int bh = blockIdx.x;
  const int b = bh / T_H, h = bh - b * T_H;
  const int t = threadIdx.x;
  if (t < 64) ql[t] = qc[(size_t)b * T_C + h * 64 + t];
  __syncthreads();
  const float* wbase = qkvw + ((size_t)T_C + h * 64) * T_C;
  double a0 = 0.0, a1 = 0.0, a2 = 0.0;
  for (int d = 0; d < 64; d++) {
    const double qd = ql[d];
    const float* wr = wbase + (size_t)d * T_C;
    a0 += qd * (double)wr[t];
    a1 += qd * (double)wr[t + 256];
    a2 += qd * (double)wr[t + 512];
  }
  double* o = wt + (size_t)bh * T_C;
  o[t] = a0; o[t + 256] = a1; o[t + 512] = a2;
}

__global__ __launch_bounds__(256) void clslog_k(const float* __restrict__ x,
                                                const double* __restrict__ wt,
                                                double* __restrict__ lg)
{
  const int b = blockIdx.x;
  const int t = threadIdx.x, w = t >> 6, lane = t & 63;

  double wreg[3][12];
#pragma unroll
  for (int i = 0; i < 3; i++) {
    const double* wb = wt + ((size_t)b * T_H + w * 3 + i) * T_C;
#pragma unroll
    for (int ci = 0; ci < 12; ci++) wreg[i][ci] = wb[lane + ci * 64];
  }

  const int n0 = blockIdx.y * 13;
  for (int nn = 0; nn < 13; nn++) {
    const int n = n0 + nn;
    if (n > 196) break;
    const float* xr = x + ((size_t)b * T_N + n) * T_C;
    double p0 = 0.0, p1 = 0.0, p2 = 0.0;
#pragma unroll
    for (int ci = 0; ci < 12; ci++) {
      const double xv = (double)xr[lane + ci * 64];
      p0 += xv * wreg[0][ci];
      p1 += xv * wreg[1][ci];
      p2 += xv * wreg[2][ci];
    }
    double pv[3] = {p0, p1, p2};
#pragma unroll
    for (int i = 0; i < 3; i++) {
      double sv = pv[i];
#pragma unroll
      for (int off = 32; off > 0; off >>= 1) sv += __shfl_xor(sv, off);
      if (lane == 0) lg[((size_t)b * T_H + w * 3 + i) * T_N + n] = sv * 0.125;
    }
  }
}

__global__ __launch_bounds__(256) void final_k(const double* __restrict__ lg,
                                               float* __restrict__ out)
{
  __shared__ double pm[12][200];
  __shared__ unsigned vals[T_NTOK];
  __shared__ int idxb[T_KEEP];
  const int b = blockIdx.x, t = threadIdx.x, w = t >> 6, lane = t & 63;
#pragma unroll
  for (int i = 0; i < 3; i++) {
    const int h = w * 3 + i;
    const double* L = lg + ((size_t)b * T_H + h) * T_N;
    double v[4]; double mx = -1e300;
#pragma unroll
    for (int t2 = 0; t2 < 4; t2++) {
      const int n = lane + t2 * 64;
      v[t2] = (n < T_N) ? L[n] : -1e300;
      mx = fmax(mx, v[t2]);
    }
#pragma unroll
    for (int off = 32; off > 0; off >>= 1) mx = fmax(mx, __shfl_xor(mx, off));
    double s = 0.0;
#pragma unroll
    for (int t2 = 0; t2 < 4; t2++) {
      const int n = lane + t2 * 64;
      const double e = (n < T_N) ? exp(v[t2] - mx) : 0.0;
      v[t2] = e; s += e;
    }
#pragma unroll
    for (int off = 32; off > 0; off >>= 1) s += __shfl_xor(s, off);
    const double inv = 1.0 / s;
#pragma unroll
    for (int t2 = 0; t2 < 4; t2++) {
      const int n = lane + t2 * 64;
      if (n < T_N) pm[h][n] = v[t2] * inv;
    }
  }
  __syncthreads();
  if (t < T_NTOK) {
    double s = 0.0;
#pragma unroll
    for (int h2 = 0; h2 < 12; h2++) s += pm[h2][t + 1];
    const float f = (float)(s / 12.0);
    vals[t] = __builtin_bit_cast(unsigned, f) & ~7u;   // 8-ulp bucket
  }
  __syncthreads();
  if (t < T_NTOK) {
    const unsigned v = vals[t];
    int r = 0;
    for (int i2 = 0; i2 < T_NTOK; i2++) {
      const unsigned vi = vals[i2];
      r += ((vi > v) || (vi == v && i2 < t)) ? 1 : 0;   // lower index first
    }
    if (r < T_KEEP) idxb[r] = t;
  }
  __syncthreads();
  if (t < T_KEEP) out[OOFF_IDX + (size_t)b * T_KEEP + t] = (float)idxb[t];
  const size_t basei = OOFF_INDEX + (size_t)b * T_KEEP * T_C;
  for (int pos = t; pos < T_KEEP * T_C; pos += 256) out[basei + pos] = (float)idxb[pos / T_C];
}

// ---------------------------------------------------------------------------
extern "C" void kernel_launch(void* const* d_in, const int* in_sizes, int n_in,
                              void* d_out, int out_size, void* d_ws, size_t ws_size,
                              hipStream_t stream)
{
  const float* x     = (const float*)d_in[0];
  const float* qkvw  = (const float*)d_in[1];
  const float* projw = (const float*)d_in[2];
  const float* projb = (const float*)d_in[3];
  float* out = (float*)d_out;

  unsigned short* u = (unsigned short*)d_ws;
  unsigned short* xb   = u + U_XB_AO;   // aliases ao (xb dead before flash)
  unsigned short* qwb  = u + U_QWB;
  unsigned short* pwb  = u + U_PWB;
  unsigned short* qb   = u + U_QB;
  unsigned short* kb   = u + U_KB;
  unsigned short* vtg  = u + U_VB;      // V transposed [bh][64][224], zero-filled
  unsigned short* ao   = u + U_XB_AO;
  double* dr  = (double*)((char*)d_ws + WS_FP_BYTE);
  double* qc  = dr;
  double* wt  = dr + 49152;
  double* lgb = dr + 49152 + 589824;

  const dim3 blk(256);

  // phase 1: FROZEN fp64 cls path -> outputs 1/2 (fp64 region dies here)
  qcls_k<<<dim3(64, 48), blk, 0, stream>>>(x, qkvw, qc);
  wtil_k<<<dim3(768), blk, 0, stream>>>(qc, qkvw, wt);
  clslog_k<<<dim3(64, 16), blk, 0, stream>>>(x, wt, lgb);
  final_k<<<dim3(64), blk, 0, stream>>>(lgb, out);

  // phase 2: bf16 pipeline -> output 0 (vtg overwrites dead fp64 tail)
  cvt_k<<<dim3(9456), blk, 0, stream>>>(x, xb);
  cvt_k<<<dim3(1728), blk, 0, stream>>>(qkvw, qwb);
  cvt_k<<<dim3(576),  blk, 0, stream>>>(projw, pwb);
  vzero_k<<<dim3(5376), blk, 0, stream>>>(vtg);
  mgemm_k<0, 18><<<dim3(99 * 18), blk, 0, stream>>>(xb, qwb, T_M, nullptr, nullptr, qb, kb, vtg);
  flash3_k<<<dim3(768), blk, 0, stream>>>(qb, kb, vtg, ao);
  mgemm_k<1, 6><<<dim3(99 * 6), blk, 0, stream>>>(ao, pwb, T_M, out, projb, nullptr, nullptr, nullptr);
}

// Round 18
// 243.288 us; speedup vs baseline: 1.7275x; 1.7275x over previous
//
#include <hip/hip_runtime.h>
#include <math.h>

// ---------------------------------------------------------------------------
// EViT attention + top-k pruning. B=64, N=197, C=768, H=12, hd=64, keep=137.
//
// out (output 0): bf16 MFMA pipeline: prep (fused cvt x/qkvw/projw + vzero)
//   -> qkv MFMA GEMM -> MFMA flash -> proj MFMA GEMM.
// idx/index (outputs 1/2): FROZEN fp64 cls path + 8-ulp-bucket low-first
//   ranking. Per-value arithmetic bit-frozen since R7.
// R18: revert mgemm to R14 (best measured: ~99us each; R15 occupancy=110,
//   R16 depth3=100, R17 reg-direct=220 all worse). GEMM surgery closed out:
//   five structural variants bracket the floor at ~99us for this shape
//   (K=768 short loop, 18% MfmaUtil, nothing saturated). Remaining harvest:
//   fuse 4 prep launches into 1 (ranges 256-aligned, no divergence).
// ---------------------------------------------------------------------------

typedef __attribute__((ext_vector_type(8))) short short8;
typedef __attribute__((ext_vector_type(4))) float f32x4;

constexpr int T_B = 64, T_N = 197, T_C = 768, T_H = 12, T_HD = 64;
constexpr int T_M = T_B * T_N;      // 12608
constexpr int T_KEEP = 137, T_NTOK = 196;

constexpr size_t OOFF_INDEX = (size_t)T_M * T_C;                        // 9,682,944
constexpr size_t OOFF_IDX   = OOFF_INDEX + (size_t)T_B * T_KEEP * T_C;  // 16,416,768

constexpr size_t U_XB_AO = 0;
constexpr size_t U_QWB   = 9682944;
constexpr size_t U_PWB   = 11452416;
constexpr size_t U_QB    = 12042240;
constexpr size_t U_KB    = 21725184;
constexpr size_t U_VB    = 31408128;          // vtg: 768*64*224 = 11,010,048 ushorts
constexpr size_t WS_FP_BYTE = 82182144ull;    // fp64 region (cls phase only)

// fused prep kernel thread-range boundaries (each множитель of 256)
constexpr int PT0 = 1210368;            // x:     9,682,944/8
constexpr int PT1 = PT0 + 221184;       // qkvw:  1,769,472/8
constexpr int PT2 = PT1 + 73728;        // projw:   589,824/8
constexpr int PT3 = PT2 + 1376256;      // vzero: 11,010,048/8  -> 11256 blocks

__device__ __forceinline__ float bf2f(short u) {
  return __builtin_bit_cast(float, ((unsigned)(unsigned short)u) << 16);
}
__device__ __forceinline__ unsigned short f2bf(float f) {
  unsigned u = __builtin_bit_cast(unsigned, f);
  return (unsigned short)((u + 0x7fffu + ((u >> 16) & 1u)) >> 16);
}

// --------------------------- fused prep: cvt x/qkvw/projw + vzero ------------
__global__ __launch_bounds__(256) void prep_k(const float* __restrict__ x,
                                              const float* __restrict__ qkvw,
                                              const float* __restrict__ projw,
                                              unsigned short* __restrict__ ws)
{
  const int gid = blockIdx.x * 256 + threadIdx.x;
  const float* src;
  unsigned short* dst;
  int idx;
  if (gid < PT0)      { src = x;     dst = ws + U_XB_AO; idx = gid; }
  else if (gid < PT1) { src = qkvw;  dst = ws + U_QWB;   idx = gid - PT0; }
  else if (gid < PT2) { src = projw; dst = ws + U_PWB;   idx = gid - PT1; }
  else {
    *(short8*)(ws + U_VB + (size_t)(gid - PT2) * 8) = (short8){0,0,0,0,0,0,0,0};
    return;
  }
  const float4 v = ((const float4*)src)[idx];
  const unsigned long long pk =
      (unsigned long long)f2bf(v.x) | ((unsigned long long)f2bf(v.y) << 16) |
      ((unsigned long long)f2bf(v.z) << 32) | ((unsigned long long)f2bf(v.w) << 48);
  ((unsigned long long*)dst)[idx] = pk;
}

// --------------------------- bf16 MFMA GEMM (R14, best measured) -------------
// C[M,N] = A[M,768] @ B[N,768]^T. 128x128 tile, BK=32, 4 waves each 64x64.
// LDS[row][s] holds global slot s ^ ((row>>1)&3); 3 bufs, counted vmcnt.
template<int MODE, int NTN>
__global__ __launch_bounds__(256) void mgemm_k(
    const unsigned short* __restrict__ A, const unsigned short* __restrict__ Bw,
    int M, float* __restrict__ outF, const float* __restrict__ bias,
    unsigned short* __restrict__ oq, unsigned short* __restrict__ ok,
    unsigned short* __restrict__ ov)
{
  __shared__ unsigned short ldsA[3][4096], ldsB[3][4096];
  const int t = threadIdx.x, w = t >> 6, lane = t & 63;
  const int wr = w >> 1, wc = w & 1;

  const int nwg = 99 * NTN;
  int id = blockIdx.x;
  {
    const int q = nwg >> 3, r = nwg & 7;
    const int xcd = id & 7, off = id >> 3;
    id = (xcd < r ? xcd * (q + 1) : r * (q + 1) + (xcd - r) * q) + off;
  }
  const int m0 = (id / NTN) * 128, n0 = (id % NTN) * 128;

  const int row0 = t >> 2,        slot0 = t & 3;
  const int row1 = 64 + (t >> 2);
  const int gs0 = slot0 ^ ((row0 >> 1) & 3);
  const int gs1 = slot0 ^ ((row1 >> 1) & 3);
  int ar0 = m0 + row0; ar0 = ar0 < M ? ar0 : M - 1;
  int ar1 = m0 + row1; ar1 = ar1 < M ? ar1 : M - 1;
  const unsigned short* Ab0 = A + (size_t)ar0 * 768 + gs0 * 8;
  const unsigned short* Ab1 = A + (size_t)ar1 * 768 + gs1 * 8;
  const unsigned short* Bb0 = Bw + (size_t)(n0 + row0) * 768 + gs0 * 8;
  const unsigned short* Bb1 = Bw + (size_t)(n0 + row1) * 768 + gs1 * 8;

  const int gsel = lane >> 4, rsel = lane & 15;
  int offA[4], offB[4];
#pragma unroll
  for (int i = 0; i < 4; i++) {
    const int rowa = wr * 64 + i * 16 + rsel;
    offA[i] = rowa * 32 + ((gsel ^ ((rowa >> 1) & 3)) * 8);
    const int rowb = wc * 64 + i * 16 + rsel;
    offB[i] = rowb * 32 + ((gsel ^ ((rowb >> 1) & 3)) * 8);
  }

  auto stage = [&](int buf, int k0) {
    __builtin_amdgcn_global_load_lds(
        (const __attribute__((address_space(1))) unsigned int*)(Ab0 + k0),
        (__attribute__((address_space(3))) unsigned int*)&ldsA[buf][(size_t)t * 8],
        16, 0, 0);
    __builtin_amdgcn_global_load_lds(
        (const __attribute__((address_space(1))) unsigned int*)(Ab1 + k0),
        (__attribute__((address_space(3))) unsigned int*)&ldsA[buf][(size_t)(256 + t) * 8],
        16, 0, 0);
    __builtin_amdgcn_global_load_lds(
        (const __attribute__((address_space(1))) unsigned int*)(Bb0 + k0),
        (__attribute__((address_space(3))) unsigned int*)&ldsB[buf][(size_t)t * 8],
        16, 0, 0);
    __builtin_amdgcn_global_load_lds(
        (const __attribute__((address_space(1))) unsigned int*)(Bb1 + k0),
        (__attribute__((address_space(3))) unsigned int*)&ldsB[buf][(size_t)(256 + t) * 8],
        16, 0, 0);
  };

  f32x4 acc[4][4];
#pragma unroll
  for (int i = 0; i < 4; i++)
#pragma unroll
    for (int j = 0; j < 4; j++) acc[i][j] = (f32x4){0.f, 0.f, 0.f, 0.f};

  stage(0, 0);
  stage(1, 32);

#pragma unroll
  for (int k = 0; k < 24; ++k) {
    __builtin_amdgcn_sched_barrier(0);
    if (k < 23) asm volatile("s_waitcnt vmcnt(4)\n\ts_barrier" ::: "memory");
    else        asm volatile("s_waitcnt vmcnt(0)\n\ts_barrier" ::: "memory");
    __builtin_amdgcn_sched_barrier(0);

    const int cur = k % 3;
    short8 aF[4], bF[4];
#pragma unroll
    for (int mi = 0; mi < 4; mi++) aF[mi] = *(const short8*)&ldsA[cur][offA[mi]];
#pragma unroll
    for (int ni = 0; ni < 4; ni++) bF[ni] = *(const short8*)&ldsB[cur][offB[ni]];

    if (k + 2 < 24) stage((k + 2) % 3, (k + 2) * 32);

#pragma unroll
    for (int mi = 0; mi < 4; mi++)
#pragma unroll
      for (int ni = 0; ni < 4; ni++)
        acc[mi][ni] = __builtin_amdgcn_mfma_f32_16x16x32_bf16(aF[mi], bF[ni], acc[mi][ni], 0, 0, 0);
  }

  const int colL = lane & 15, rowH = lane >> 4;
#pragma unroll
  for (int mi = 0; mi < 4; mi++) {
#pragma unroll
    for (int r = 0; r < 4; r++) {
      const int gm = m0 + wr * 64 + mi * 16 + rowH * 4 + r;
      if (gm >= M) continue;
      int bb = 0, nn = 0;
      if (MODE == 0) { bb = gm / T_N; nn = gm - bb * T_N; }
#pragma unroll
      for (int ni = 0; ni < 4; ni++) {
        const int gc = n0 + wc * 64 + ni * 16 + colL;
        const float val = acc[mi][ni][r];
        if (MODE == 0) {
          const int part = gc / T_C;
          const int rem = gc - part * T_C;
          const int h = rem >> 6, d = rem & 63;
          if (part == 2) {
            ov[(((size_t)(bb * T_H + h)) * 64 + d) * 224 + nn] = f2bf(val);
          } else {
            unsigned short* dst = part == 0 ? oq : ok;
            dst[(((size_t)(bb * T_H + h)) * T_N + nn) * T_HD + d] = f2bf(val);
          }
        } else {
          outF[(size_t)gm * T_C + gc] = val + bias[gc];
        }
      }
    }
  }
}

// --------------------------- MFMA flash attention (R12) ----------------------
__global__ __launch_bounds__(256) void flash3_k(
    const unsigned short* __restrict__ qb, const unsigned short* __restrict__ kb,
    const unsigned short* __restrict__ vtg, unsigned short* __restrict__ ao)
{
  __shared__ unsigned short lds[27456];   // K 12608 + 4 x P 3712
  constexpr int KL_U = 0;
  constexpr int PL0  = 12608;

  const int bh = blockIdx.x;
  const int b = bh / T_H, h = bh - b * T_H;
  const int t = threadIdx.x;
  const int w = t >> 6, lane = t & 63;
  const int colL = lane & 15, g4 = lane >> 4;
  const int PL_W = PL0 + w * 3712;
  const short8 z8 = (short8){0, 0, 0, 0, 0, 0, 0, 0};

  {
    const unsigned short* src = kb + (size_t)bh * T_N * 64;
    for (int c = t; c < 1576; c += 256) {
      const int row = c >> 3, s = c & 7;
      const short8 v = *(const short8*)(src + row * 64 + s * 8);
      *(short8*)&lds[KL_U + row * 64 + ((s ^ (row & 7)) * 8)] = v;
    }
  }
  if (lane < 16) {
    unsigned short* p = &lds[PL_W + lane * 232];
    *(short8*)&p[208] = z8; *(short8*)&p[216] = z8;
  }
  __syncthreads();

  const size_t qbase = (size_t)bh * T_N * 64;
  const unsigned short* vb2 = vtg + (size_t)bh * 64 * 224;

  for (int qt = w; qt < 13; qt += 4) {
    int qrow = qt * 16 + colL; if (qrow > 196) qrow = 196;
    const short8 qa0 = *(const short8*)(qb + qbase + (size_t)qrow * 64 + g4 * 8);
    const short8 qa1 = *(const short8*)(qb + qbase + (size_t)qrow * 64 + 32 + g4 * 8);

    f32x4 acc[13];
#pragma unroll
    for (int kt = 0; kt < 13; kt++) acc[kt] = (f32x4){0.f, 0.f, 0.f, 0.f};
#pragma unroll
    for (int kt = 0; kt < 13; kt++) {
      const int krow = kt * 16 + colL;
      const int base = KL_U + krow * 64;
      const short8 k0f = *(const short8*)&lds[base + ((g4 ^ (krow & 7)) * 8)];
      const short8 k1f = *(const short8*)&lds[base + (((4 + g4) ^ (krow & 7)) * 8)];
      acc[kt] = __builtin_amdgcn_mfma_f32_16x16x32_bf16(qa0, k0f, acc[kt], 0, 0, 0);
      acc[kt] = __builtin_amdgcn_mfma_f32_16x16x32_bf16(qa1, k1f, acc[kt], 0, 0, 0);
    }

    float l4[4];
#pragma unroll
    for (int r = 0; r < 4; r++) {
      float sv[13];
      float mx = -1e30f;
#pragma unroll
      for (int kt = 0; kt < 13; kt++) {
        const int col = kt * 16 + colL;
        float s = acc[kt][r] * 0.125f;
        if (col > 196) s = -1e30f;
        sv[kt] = s;
        mx = fmaxf(mx, s);
      }
      mx = fmaxf(mx, __shfl_xor(mx, 1));
      mx = fmaxf(mx, __shfl_xor(mx, 2));
      mx = fmaxf(mx, __shfl_xor(mx, 4));
      mx = fmaxf(mx, __shfl_xor(mx, 8));
      float l = 0.f;
      const int prow = g4 * 4 + r;
#pragma unroll
      for (int kt = 0; kt < 13; kt++) {
        const float p = __expf(sv[kt] - mx);
        l += p;
        lds[PL_W + prow * 232 + kt * 16 + colL] = f2bf(p);
      }
      l += __shfl_xor(l, 1);
      l += __shfl_xor(l, 2);
      l += __shfl_xor(l, 4);
      l += __shfl_xor(l, 8);
      l4[r] = l;
    }

    f32x4 oacc[4];
#pragma unroll
    for (int dt = 0; dt < 4; dt++) oacc[dt] = (f32x4){0.f, 0.f, 0.f, 0.f};
#pragma unroll
    for (int ks = 0; ks < 7; ks++) {
      const short8 pa = *(const short8*)&lds[PL_W + colL * 232 + ks * 32 + g4 * 8];
#pragma unroll
      for (int dt = 0; dt < 4; dt++) {
        const short8 vf = *(const short8*)(vb2 + (size_t)(dt * 16 + colL) * 224 + ks * 32 + g4 * 8);
        oacc[dt] = __builtin_amdgcn_mfma_f32_16x16x32_bf16(pa, vf, oacc[dt], 0, 0, 0);
      }
    }

#pragma unroll
    for (int r = 0; r < 4; r++) {
      const int row = qt * 16 + g4 * 4 + r;
      if (row <= 196) {
        const float invl = 1.f / l4[r];
        unsigned short* op = ao + ((size_t)b * T_N + row) * T_C + h * 64;
#pragma unroll
        for (int dt = 0; dt < 4; dt++)
          op[dt * 16 + colL] = f2bf(oacc[dt][r] * invl);
      }
    }
  }
}

// --------------------------- fp64 cls path (FROZEN arithmetic) ---------------
__global__ __launch_bounds__(256) void qcls_k(const float* __restrict__ x,
                                              const float* __restrict__ qkvw,
                                              double* __restrict__ qc)
{
  __shared__ double xr[768];
  const int b = blockIdx.x, t = threadIdx.x;
  if (t < 192) {
    const float4 v = *(const float4*)&x[(size_t)b * T_N * T_C + t * 4];
    xr[t * 4 + 0] = (double)v.x; xr[t * 4 + 1] = (double)v.y;
    xr[t * 4 + 2] = (double)v.z; xr[t * 4 + 3] = (double)v.w;
  }
  __syncthreads();
  const int w = t >> 6, lane = t & 63;
  const int jj0 = blockIdx.y * 4;
  for (int jj = jj0; jj < jj0 + 4; jj++) {
    const int j = jj * 4 + w;
    const float* wr = qkvw + (size_t)j * T_C;
    double a = 0.0;
#pragma unroll
    for (int ci = 0; ci < 12; ci++) a += xr[lane + ci * 64] * (double)wr[lane + ci * 64];
#pragma unroll
    for (int off = 32; off > 0; off >>= 1) a += __shfl_xor(a, off);
    if (lane == 0) qc[(size_t)b * T_C + j] = a;
  }
}

__global__ __launch_bounds__(256) void wtil_k(const double* __restrict__ qc,
                                              const float* __restrict__ qkvw,
                                              double* __restrict__ wt)
{
  __shared__ double ql[64];
  const int bh = blockIdx.x;
  const int b = bh / T_H, h = bh - b * T_H;
  const int t = threadIdx.x;
  if (t < 64) ql[t] = qc[(size_t)b * T_C + h * 64 + t];
  __syncthreads();
  const float* wbase = qkvw + ((size_t)T_C + h * 64) * T_C;
  double a0 = 0.0, a1 = 0.0, a2 = 0.0;
  for (int d = 0; d < 64; d++) {
    const double qd = ql[d];
    const float* wr = wbase + (size_t)d * T_C;
    a0 += qd * (double)wr[t];
    a1 += qd * (double)wr[t + 256];
    a2 += qd * (double)wr[t + 512];
  }
  double* o = wt + (size_t)bh * T_C;
  o[t] = a0; o[t + 256] = a1; o[t + 512] = a2;
}

__global__ __launch_bounds__(256) void clslog_k(const float* __restrict__ x,
                                                const double* __restrict__ wt,
                                                double* __restrict__ lg)
{
  const int b = blockIdx.x;
  const int t = threadIdx.x, w = t >> 6, lane = t & 63;

  double wreg[3][12];
#pragma unroll
  for (int i = 0; i < 3; i++) {
    const double* wb = wt + ((size_t)b * T_H + w * 3 + i) * T_C;
#pragma unroll
    for (int ci = 0; ci < 12; ci++) wreg[i][ci] = wb[lane + ci * 64];
  }

  const int n0 = blockIdx.y * 13;
  for (int nn = 0; nn < 13; nn++) {
    const int n = n0 + nn;
    if (n > 196) break;
    const float* xr = x + ((size_t)b * T_N + n) * T_C;
    double p0 = 0.0, p1 = 0.0, p2 = 0.0;
#pragma unroll
    for (int ci = 0; ci < 12; ci++) {
      const double xv = (double)xr[lane + ci * 64];
      p0 += xv * wreg[0][ci];
      p1 += xv * wreg[1][ci];
      p2 += xv * wreg[2][ci];
    }
    double pv[3] = {p0, p1, p2};
#pragma unroll
    for (int i = 0; i < 3; i++) {
      double sv = pv[i];
#pragma unroll
      for (int off = 32; off > 0; off >>= 1) sv += __shfl_xor(sv, off);
      if (lane == 0) lg[((size_t)b * T_H + w * 3 + i) * T_N + n] = sv * 0.125;
    }
  }
}

__global__ __launch_bounds__(256) void final_k(const double* __restrict__ lg,
                                               float* __restrict__ out)
{
  __shared__ double pm[12][200];
  __shared__ unsigned vals[T_NTOK];
  __shared__ int idxb[T_KEEP];
  const int b = blockIdx.x, t = threadIdx.x, w = t >> 6, lane = t & 63;
#pragma unroll
  for (int i = 0; i < 3; i++) {
    const int h = w * 3 + i;
    const double* L = lg + ((size_t)b * T_H + h) * T_N;
    double v[4]; double mx = -1e300;
#pragma unroll
    for (int t2 = 0; t2 < 4; t2++) {
      const int n = lane + t2 * 64;
      v[t2] = (n < T_N) ? L[n] : -1e300;
      mx = fmax(mx, v[t2]);
    }
#pragma unroll
    for (int off = 32; off > 0; off >>= 1) mx = fmax(mx, __shfl_xor(mx, off));
    double s = 0.0;
#pragma unroll
    for (int t2 = 0; t2 < 4; t2++) {
      const int n = lane + t2 * 64;
      const double e = (n < T_N) ? exp(v[t2] - mx) : 0.0;
      v[t2] = e; s += e;
    }
#pragma unroll
    for (int off = 32; off > 0; off >>= 1) s += __shfl_xor(s, off);
    const double inv = 1.0 / s;
#pragma unroll
    for (int t2 = 0; t2 < 4; t2++) {
      const int n = lane + t2 * 64;
      if (n < T_N) pm[h][n] = v[t2] * inv;
    }
  }
  __syncthreads();
  if (t < T_NTOK) {
    double s = 0.0;
#pragma unroll
    for (int h2 = 0; h2 < 12; h2++) s += pm[h2][t + 1];
    const float f = (float)(s / 12.0);
    vals[t] = __builtin_bit_cast(unsigned, f) & ~7u;   // 8-ulp bucket
  }
  __syncthreads();
  if (t < T_NTOK) {
    const unsigned v = vals[t];
    int r = 0;
    for (int i2 = 0; i2 < T_NTOK; i2++) {
      const unsigned vi = vals[i2];
      r += ((vi > v) || (vi == v && i2 < t)) ? 1 : 0;   // lower index first
    }
    if (r < T_KEEP) idxb[r] = t;
  }
  __syncthreads();
  if (t < T_KEEP) out[OOFF_IDX + (size_t)b * T_KEEP + t] = (float)idxb[t];
  const size_t basei = OOFF_INDEX + (size_t)b * T_KEEP * T_C;
  for (int pos = t; pos < T_KEEP * T_C; pos += 256) out[basei + pos] = (float)idxb[pos / T_C];
}

// ---------------------------------------------------------------------------
extern "C" void kernel_launch(void* const* d_in, const int* in_sizes, int n_in,
                              void* d_out, int out_size, void* d_ws, size_t ws_size,
                              hipStream_t stream)
{
  const float* x     = (const float*)d_in[0];
  const float* qkvw  = (const float*)d_in[1];
  const float* projw = (const float*)d_in[2];
  const float* projb = (const float*)d_in[3];
  float* out = (float*)d_out;

  unsigned short* u = (unsigned short*)d_ws;
  unsigned short* xb   = u + U_XB_AO;   // aliases ao (xb dead before flash)
  unsigned short* qwb  = u + U_QWB;
  unsigned short* pwb  = u + U_PWB;
  unsigned short* qb   = u + U_QB;
  unsigned short* kb   = u + U_KB;
  unsigned short* vtg  = u + U_VB;      // V transposed [bh][64][224], zero-filled
  unsigned short* ao   = u + U_XB_AO;
  double* dr  = (double*)((char*)d_ws + WS_FP_BYTE);
  double* qc  = dr;
  double* wt  = dr + 49152;
  double* lgb = dr + 49152 + 589824;

  const dim3 blk(256);

  // phase 1: FROZEN fp64 cls path -> outputs 1/2 (fp64 region dies here)
  qcls_k<<<dim3(64, 48), blk, 0, stream>>>(x, qkvw, qc);
  wtil_k<<<dim3(768), blk, 0, stream>>>(qc, qkvw, wt);
  clslog_k<<<dim3(64, 16), blk, 0, stream>>>(x, wt, lgb);
  final_k<<<dim3(64), blk, 0, stream>>>(lgb, out);

  // phase 2: bf16 pipeline -> output 0 (vtg overwrites dead fp64 tail)
  prep_k<<<dim3(PT3 / 256), blk, 0, stream>>>(x, qkvw, projw, u);
  mgemm_k<0, 18><<<dim3(99 * 18), blk, 0, stream>>>(xb, qwb, T_M, nullptr, nullptr, qb, kb, vtg);
  flash3_k<<<dim3(768), blk, 0, stream>>>(qb, kb, vtg, ao);
  mgemm_k<1, 6><<<dim3(99 * 6), blk, 0, stream>>>(ao, pwb, T_M, out, projb, nullptr, nullptr, nullptr);
}